// Round 1
// 481.264 us; speedup vs baseline: 1.0457x; 1.0457x over previous
//
#include <hip/hip_runtime.h>

#define N_POINTS 1048576
#define FEAT 64
#define RES 256
#define PLANE_ELEMS (FEAT * RES * RES)  // elements per plane (4.19M)

// Morton bucketing: 32 buckets per axis -> 32768 buckets, ~32 points each.
#define BUCKET_G 32
#define NBUCKET (BUCKET_G * BUCKET_G * BUCKET_G)

// Sorted sample kernel geometry: 32 points/block (8 lanes/point, 256 thr).
#define SAMPLE_BLOCKS (N_POINTS / 32)          // 32768
#define SAMPLE_CPX (SAMPLE_BLOCKS / 8)         // 4096 blocks per XCD chunk

typedef unsigned short ushort_t;
typedef float v4f __attribute__((ext_vector_type(4)));  // native vec for nt ops

// round-to-nearest-even float -> bf16 bits
__device__ __forceinline__ ushort_t f2bf(float f) {
  unsigned u = __float_as_uint(f);
  unsigned r = u + 0x7FFFu + ((u >> 16) & 1u);
  return (ushort_t)(r >> 16);
}

// ---------------------------------------------------------------------------
// Transpose + convert: fp32 [C=64, H*W] -> bf16 [H*W, C=64].  (unchanged)
// ---------------------------------------------------------------------------
__global__ __launch_bounds__(256) void transpose_bf16(
    const float* __restrict__ pxy, const float* __restrict__ pxz,
    const float* __restrict__ pyz, ushort_t* __restrict__ dst) {
  __shared__ ushort_t tile[64][72];  // [p][c]
  const int plane = blockIdx.y;
  const float* src = (plane == 0) ? pxy : ((plane == 1) ? pxz : pyz);
  ushort_t* out = dst + (size_t)plane * PLANE_ELEMS;
  const int p0 = blockIdx.x * 64;
  const int tid = threadIdx.x;
#pragma unroll
  for (int k = 0; k < 4; ++k) {
    int c = (tid >> 4) + k * 16;  // 0..63
    int pp = (tid & 15) * 4;      // 0..60, float4-aligned
    float4 v = *(const float4*)(src + (size_t)c * (RES * RES) + p0 + pp);
    tile[pp + 0][c] = f2bf(v.x);
    tile[pp + 1][c] = f2bf(v.y);
    tile[pp + 2][c] = f2bf(v.z);
    tile[pp + 3][c] = f2bf(v.w);
  }
  __syncthreads();
#pragma unroll
  for (int k = 0; k < 2; ++k) {
    int idx = k * 256 + tid;
    int pp = idx >> 3;            // 0..63
    int c8 = (idx & 7) * 8;       // 0..56
    uint4 v = *(const uint4*)&tile[pp][c8];  // 16B-aligned LDS read
    *(uint4*)(out + (size_t)(p0 + pp) * FEAT + c8) = v;
  }
}

// ---------------------------------------------------------------------------
// Morton bucket helpers
// ---------------------------------------------------------------------------
__device__ __forceinline__ unsigned part1by2(unsigned v) {
  // spread low 5 bits to every 3rd bit position (standard 10-bit spread)
  v &= 0x3FFu;
  v = (v | (v << 16)) & 0x030000FFu;
  v = (v | (v << 8)) & 0x0300F00Fu;
  v = (v | (v << 4)) & 0x030C30C3u;
  v = (v | (v << 2)) & 0x09249249u;
  return v;
}

__device__ __forceinline__ unsigned morton_bucket(float px, float py, float pz) {
  int bx = (int)((px + 1.0f) * (0.5f * BUCKET_G));
  int by = (int)((py + 1.0f) * (0.5f * BUCKET_G));
  int bz = (int)((pz + 1.0f) * (0.5f * BUCKET_G));
  bx = min(max(bx, 0), BUCKET_G - 1);
  by = min(max(by, 0), BUCKET_G - 1);
  bz = min(max(bz, 0), BUCKET_G - 1);
  return part1by2((unsigned)bx) | (part1by2((unsigned)by) << 1) |
         (part1by2((unsigned)bz) << 2);  // < 32768
}

__global__ __launch_bounds__(256) void zero_hist(unsigned* __restrict__ h) {
  h[blockIdx.x * 256 + threadIdx.x] = 0u;
}

__global__ __launch_bounds__(256) void bucket_count(
    const float* __restrict__ x, unsigned* __restrict__ hist) {
  int n = blockIdx.x * 256 + threadIdx.x;
  float px = x[n * 3 + 0];
  float py = x[n * 3 + 1];
  float pz = x[n * 3 + 2];
  atomicAdd(&hist[morton_bucket(px, py, pz)], 1u);
}

// Exclusive prefix sum over NBUCKET=32768 counts. One block of 1024 threads,
// 32 counts per thread serial + Hillis-Steele block scan of the 1024 partials.
__global__ __launch_bounds__(1024) void scan_hist(
    const unsigned* __restrict__ hist, unsigned* __restrict__ cursor) {
  __shared__ unsigned part[1024];
  const int tid = threadIdx.x;
  unsigned local[32];
  unsigned s = 0;
#pragma unroll
  for (int i = 0; i < 32; ++i) {
    local[i] = s;                 // exclusive within chunk
    s += hist[tid * 32 + i];
  }
  part[tid] = s;
  __syncthreads();
  for (int off = 1; off < 1024; off <<= 1) {
    unsigned add = (tid >= off) ? part[tid - off] : 0u;
    __syncthreads();
    part[tid] += add;
    __syncthreads();
  }
  unsigned base = (tid == 0) ? 0u : part[tid - 1];
#pragma unroll
  for (int i = 0; i < 32; ++i) cursor[tid * 32 + i] = base + local[i];
}

// Scatter points into bucket-sorted order: xs[pos] = (px,py,pz, bitcast(n)).
__global__ __launch_bounds__(256) void bucket_scatter(
    const float* __restrict__ x, unsigned* __restrict__ cursor,
    float4* __restrict__ xs) {
  int n = blockIdx.x * 256 + threadIdx.x;
  float px = x[n * 3 + 0];
  float py = x[n * 3 + 1];
  float pz = x[n * 3 + 2];
  unsigned b = morton_bucket(px, py, pz);
  unsigned pos = atomicAdd(&cursor[b], 1u);
  xs[pos] = make_float4(px, py, pz, __uint_as_float((unsigned)n));
}

// ---------------------------------------------------------------------------
// Sampling core: 8 lanes/point, each lane owns 8 channels (ushort8 = 16 B).
// Corner gather = 8 lanes x 16 B = 128 B contiguous (one cell line).
// ---------------------------------------------------------------------------
__device__ __forceinline__ void unpack_fma(uint4 v, float w, float* acc) {
  acc[0] = fmaf(__uint_as_float(v.x << 16), w, acc[0]);
  acc[1] = fmaf(__uint_as_float(v.x & 0xFFFF0000u), w, acc[1]);
  acc[2] = fmaf(__uint_as_float(v.y << 16), w, acc[2]);
  acc[3] = fmaf(__uint_as_float(v.y & 0xFFFF0000u), w, acc[3]);
  acc[4] = fmaf(__uint_as_float(v.z << 16), w, acc[4]);
  acc[5] = fmaf(__uint_as_float(v.z & 0xFFFF0000u), w, acc[5]);
  acc[6] = fmaf(__uint_as_float(v.w << 16), w, acc[6]);
  acc[7] = fmaf(__uint_as_float(v.w & 0xFFFF0000u), w, acc[7]);
}

__device__ __forceinline__ void sample_plane(const ushort_t* __restrict__ tp,
                                             float u, float v, int c8,
                                             float* acc) {
  float ix = (u + 1.0f) * 0.5f * (float)(RES - 1);
  float iy = (v + 1.0f) * 0.5f * (float)(RES - 1);
  float fx0 = floorf(ix), fy0 = floorf(iy);
  // weights from UNCLAMPED floor coords (reference semantics)
  float wx1 = ix - fx0, wy1 = iy - fy0;
  float wx0 = fx0 + 1.0f - ix, wy0 = fy0 + 1.0f - iy;
  int x0 = min(max((int)fx0, 0), RES - 1);
  int y0 = min(max((int)fy0, 0), RES - 1);
  int x1 = min(max((int)fx0 + 1, 0), RES - 1);
  int y1 = min(max((int)fy0 + 1, 0), RES - 1);

  const uint4 v00 = *(const uint4*)(tp + (size_t)(y0 * RES + x0) * FEAT + c8);
  const uint4 v01 = *(const uint4*)(tp + (size_t)(y0 * RES + x1) * FEAT + c8);
  const uint4 v10 = *(const uint4*)(tp + (size_t)(y1 * RES + x0) * FEAT + c8);
  const uint4 v11 = *(const uint4*)(tp + (size_t)(y1 * RES + x1) * FEAT + c8);

  unpack_fma(v00, wx0 * wy0, acc);
  unpack_fma(v01, wx1 * wy0, acc);
  unpack_fma(v10, wx0 * wy1, acc);
  unpack_fma(v11, wx1 * wy1, acc);
}

// ---------------------------------------------------------------------------
// Sorted sampling: block b (XCD-chunk swizzled) handles 32 consecutive
// bucket-sorted points. Each XCD works one Morton octant (~6.4 MB footprint
// across the 3 planes) -> gathers hit the private 4 MB L2.
// ---------------------------------------------------------------------------
__global__ __launch_bounds__(256) void triplane_sample_sorted(
    const float4* __restrict__ xs, const ushort_t* __restrict__ tps,
    float* __restrict__ out) {
  int bid = blockIdx.x;
  int swz = (bid & 7) * SAMPLE_CPX + (bid >> 3);  // XCD-chunked (bijective)
  int p = swz * 32 + (threadIdx.x >> 3);          // sorted point slot
  int c8 = (threadIdx.x & 7) << 3;                // channel group base

  v4f pt = __builtin_nontemporal_load((const v4f*)xs + p);  // 8 lanes share
  unsigned n = __float_as_uint(pt.w);             // original point index

  float acc[8] = {0.f, 0.f, 0.f, 0.f, 0.f, 0.f, 0.f, 0.f};
  sample_plane(tps, pt.x, pt.y, c8, acc);                    // xy: (x, y)
  sample_plane(tps + PLANE_ELEMS, pt.x, pt.z, c8, acc);      // xz: (x, z)
  sample_plane(tps + 2 * PLANE_ELEMS, pt.y, pt.z, c8, acc);  // yz: (y, z)

  const float s = 1.0f / 3.0f;
  v4f lo = {acc[0] * s, acc[1] * s, acc[2] * s, acc[3] * s};
  v4f hi = {acc[4] * s, acc[5] * s, acc[6] * s, acc[7] * s};
  float* o = out + (size_t)n * FEAT + c8;
  __builtin_nontemporal_store(lo, (v4f*)o);
  __builtin_nontemporal_store(hi, (v4f*)(o + 4));
}

// ---------------------------------------------------------------------------
// Unsorted fallback (previous best kernel): ws fits atlas but not sort bufs.
// ---------------------------------------------------------------------------
__global__ __launch_bounds__(256) void triplane_sample_bf16(
    const float* __restrict__ x, const ushort_t* __restrict__ tps,
    float* __restrict__ out) {
  int t = blockIdx.x * 256 + threadIdx.x;
  int n = t >> 3;
  int c8 = (t & 7) << 3;
  float px = __builtin_nontemporal_load(x + n * 3 + 0);
  float py = __builtin_nontemporal_load(x + n * 3 + 1);
  float pz = __builtin_nontemporal_load(x + n * 3 + 2);
  float acc[8] = {0.f, 0.f, 0.f, 0.f, 0.f, 0.f, 0.f, 0.f};
  sample_plane(tps, px, py, c8, acc);
  sample_plane(tps + PLANE_ELEMS, px, pz, c8, acc);
  sample_plane(tps + 2 * PLANE_ELEMS, py, pz, c8, acc);
  const float s = 1.0f / 3.0f;
  v4f lo = {acc[0] * s, acc[1] * s, acc[2] * s, acc[3] * s};
  v4f hi = {acc[4] * s, acc[5] * s, acc[6] * s, acc[7] * s};
  float* o = out + (size_t)n * FEAT + c8;
  __builtin_nontemporal_store(lo, (v4f*)o);
  __builtin_nontemporal_store(hi, (v4f*)(o + 4));
}

// ---------------------------------------------------------------------------
// Last-resort fallback: direct gather from native [C,H,W] layout.
// ---------------------------------------------------------------------------
__device__ __forceinline__ float sample_one(const float* __restrict__ pc,
                                            float u, float v) {
  float ix = (u + 1.0f) * 0.5f * (float)(RES - 1);
  float iy = (v + 1.0f) * 0.5f * (float)(RES - 1);
  float fx0 = floorf(ix), fy0 = floorf(iy);
  float wx1 = ix - fx0, wy1 = iy - fy0;
  float wx0 = fx0 + 1.0f - ix, wy0 = fy0 + 1.0f - iy;
  int x0 = min(max((int)fx0, 0), RES - 1);
  int y0 = min(max((int)fy0, 0), RES - 1);
  int x1 = min(max((int)fx0 + 1, 0), RES - 1);
  int y1 = min(max((int)fy0 + 1, 0), RES - 1);
  return pc[y0 * RES + x0] * (wx0 * wy0) + pc[y0 * RES + x1] * (wx1 * wy0) +
         pc[y1 * RES + x0] * (wx0 * wy1) + pc[y1 * RES + x1] * (wx1 * wy1);
}

__global__ __launch_bounds__(256) void triplane_direct(
    const float* __restrict__ x, const float* __restrict__ pxy,
    const float* __restrict__ pxz, const float* __restrict__ pyz,
    float* __restrict__ out) {
  int t = blockIdx.x * 256 + threadIdx.x;
  int n = t >> 6;
  int c = t & 63;
  float px = x[n * 3 + 0];
  float py = x[n * 3 + 1];
  float pz = x[n * 3 + 2];
  const size_t cs = (size_t)c * (RES * RES);
  float acc = sample_one(pxy + cs, px, py) + sample_one(pxz + cs, px, pz) +
              sample_one(pyz + cs, py, pz);
  out[(size_t)n * FEAT + c] = acc * (1.0f / 3.0f);
}

extern "C" void kernel_launch(void* const* d_in, const int* in_sizes, int n_in,
                              void* d_out, int out_size, void* d_ws,
                              size_t ws_size, hipStream_t stream) {
  const float* x   = (const float*)d_in[0];
  const float* pxy = (const float*)d_in[1];
  const float* pxz = (const float*)d_in[2];
  const float* pyz = (const float*)d_in[3];
  float* out = (float*)d_out;

  const size_t tps_bytes = (size_t)3 * PLANE_ELEMS * sizeof(ushort_t);  // 24 MB
  const size_t xs_bytes  = (size_t)N_POINTS * sizeof(float4);           // 16 MB
  const size_t cnt_bytes = (size_t)NBUCKET * sizeof(unsigned);          // 128 KB
  const size_t need_sorted = tps_bytes + xs_bytes + 2 * cnt_bytes;      // ~40.3 MB

  if (ws_size >= need_sorted) {
    ushort_t* tps    = (ushort_t*)d_ws;
    float4* xs       = (float4*)((char*)d_ws + tps_bytes);
    unsigned* cursor = (unsigned*)((char*)d_ws + tps_bytes + xs_bytes);
    unsigned* hist   = cursor + NBUCKET;

    dim3 tgrid(RES * RES / 64, 3);
    transpose_bf16<<<tgrid, 256, 0, stream>>>(pxy, pxz, pyz, tps);
    zero_hist<<<NBUCKET / 256, 256, 0, stream>>>(hist);
    bucket_count<<<N_POINTS / 256, 256, 0, stream>>>(x, hist);
    scan_hist<<<1, 1024, 0, stream>>>(hist, cursor);
    bucket_scatter<<<N_POINTS / 256, 256, 0, stream>>>(x, cursor, xs);
    triplane_sample_sorted<<<SAMPLE_BLOCKS, 256, 0, stream>>>(xs, tps, out);
  } else if (ws_size >= tps_bytes) {
    ushort_t* tps = (ushort_t*)d_ws;
    dim3 tgrid(RES * RES / 64, 3);
    transpose_bf16<<<tgrid, 256, 0, stream>>>(pxy, pxz, pyz, tps);
    triplane_sample_bf16<<<(N_POINTS * 8) / 256, 256, 0, stream>>>(x, tps, out);
  } else {
    triplane_direct<<<(N_POINTS * 64) / 256, 256, 0, stream>>>(x, pxy, pxz,
                                                               pyz, out);
  }
}

// Round 3
// 472.496 us; speedup vs baseline: 1.0651x; 1.0186x over previous
//
#include <hip/hip_runtime.h>

#define N_POINTS 1048576
#define FEAT 64
#define RES 256
#define PLANE_ELEMS (FEAT * RES * RES)  // elements per plane (4.19M)

// Morton bucketing: 32 buckets per axis -> 32768 buckets, ~32 points each.
#define BUCKET_G 32
#define NBUCKET (BUCKET_G * BUCKET_G * BUCKET_G)

// Sorted sample kernel geometry: 32 points/block (8 lanes/point, 256 thr).
#define SAMPLE_BLOCKS (N_POINTS / 32)          // 32768
#define SAMPLE_CPX (SAMPLE_BLOCKS / 8)         // 4096 blocks per XCD chunk

// Fused prep kernel: first TRANSPOSE_BLOCKS do transpose, rest do bucket count.
#define TRANSPOSE_BLOCKS (3 * (RES * RES / 64))      // 3072
#define COUNT_BLOCKS (N_POINTS / 256)                // 4096
#define PREP_BLOCKS (TRANSPOSE_BLOCKS + COUNT_BLOCKS)

typedef unsigned short ushort_t;
typedef float v4f __attribute__((ext_vector_type(4)));       // native 16B vec
typedef _Float16 half8 __attribute__((ext_vector_type(8)));  // 8 fp16 = 16 B

// float -> fp16 bits (RTNE)
__device__ __forceinline__ ushort_t f2h(float f) {
  _Float16 h = (_Float16)f;
  return __builtin_bit_cast(unsigned short, h);
}

// ---------------------------------------------------------------------------
// Morton bucket helpers
// ---------------------------------------------------------------------------
__device__ __forceinline__ unsigned part1by2(unsigned v) {
  v &= 0x3FFu;
  v = (v | (v << 16)) & 0x030000FFu;
  v = (v | (v << 8)) & 0x0300F00Fu;
  v = (v | (v << 4)) & 0x030C30C3u;
  v = (v | (v << 2)) & 0x09249249u;
  return v;
}

__device__ __forceinline__ unsigned morton_bucket(float px, float py, float pz) {
  int bx = (int)((px + 1.0f) * (0.5f * BUCKET_G));
  int by = (int)((py + 1.0f) * (0.5f * BUCKET_G));
  int bz = (int)((pz + 1.0f) * (0.5f * BUCKET_G));
  bx = min(max(bx, 0), BUCKET_G - 1);
  by = min(max(by, 0), BUCKET_G - 1);
  bz = min(max(bz, 0), BUCKET_G - 1);
  return part1by2((unsigned)bx) | (part1by2((unsigned)by) << 1) |
         (part1by2((unsigned)bz) << 2);  // < 32768
}

// ---------------------------------------------------------------------------
// Fused prep: blocks [0,3072) transpose fp32 [C,H*W] -> fp16 [H*W,C];
// blocks [3072,7168) histogram the Morton buckets. Independent work
// overlaps across CUs instead of serializing as two launches.
// ---------------------------------------------------------------------------
__global__ __launch_bounds__(256) void prep_transpose_count(
    const float* __restrict__ pxy, const float* __restrict__ pxz,
    const float* __restrict__ pyz, ushort_t* __restrict__ dst,
    const float* __restrict__ x, unsigned* __restrict__ hist) {
  const int b = blockIdx.x;
  const int tid = threadIdx.x;
  if (b >= TRANSPOSE_BLOCKS) {
    // ---- bucket count ----
    int n = (b - TRANSPOSE_BLOCKS) * 256 + tid;
    float px = x[n * 3 + 0];
    float py = x[n * 3 + 1];
    float pz = x[n * 3 + 2];
    atomicAdd(&hist[morton_bucket(px, py, pz)], 1u);
    return;
  }
  // ---- transpose + fp32->fp16 ----
  __shared__ ushort_t tile[64][72];  // [p][c], row = 144 B (16B-aligned)
  const int plane = b >> 10;                  // 0..2
  const int p0 = (b & 1023) * 64;
  const float* src = (plane == 0) ? pxy : ((plane == 1) ? pxz : pyz);
  ushort_t* out = dst + (size_t)plane * PLANE_ELEMS;
#pragma unroll
  for (int k = 0; k < 4; ++k) {
    int c = (tid >> 4) + k * 16;  // 0..63
    int pp = (tid & 15) * 4;      // 0..60, float4-aligned
    v4f v = __builtin_nontemporal_load(
        (const v4f*)(src + (size_t)c * (RES * RES) + p0 + pp));
    tile[pp + 0][c] = f2h(v.x);
    tile[pp + 1][c] = f2h(v.y);
    tile[pp + 2][c] = f2h(v.z);
    tile[pp + 3][c] = f2h(v.w);
  }
  __syncthreads();
#pragma unroll
  for (int k = 0; k < 2; ++k) {
    int idx = k * 256 + tid;
    int pp = idx >> 3;            // 0..63
    int c8 = (idx & 7) * 8;       // 0..56
    uint4 v = *(const uint4*)&tile[pp][c8];  // 16B-aligned LDS read
    *(uint4*)(out + (size_t)(p0 + pp) * FEAT + c8) = v;
  }
}

// Exclusive prefix sum over NBUCKET=32768 counts. One block of 1024 threads,
// 32 counts per thread serial + Hillis-Steele block scan of the 1024 partials.
__global__ __launch_bounds__(1024) void scan_hist(
    const unsigned* __restrict__ hist, unsigned* __restrict__ cursor) {
  __shared__ unsigned part[1024];
  const int tid = threadIdx.x;
  unsigned local[32];
  unsigned s = 0;
#pragma unroll
  for (int i = 0; i < 32; ++i) {
    local[i] = s;                 // exclusive within chunk
    s += hist[tid * 32 + i];
  }
  part[tid] = s;
  __syncthreads();
  for (int off = 1; off < 1024; off <<= 1) {
    unsigned add = (tid >= off) ? part[tid - off] : 0u;
    __syncthreads();
    part[tid] += add;
    __syncthreads();
  }
  unsigned base = (tid == 0) ? 0u : part[tid - 1];
#pragma unroll
  for (int i = 0; i < 32; ++i) cursor[tid * 32 + i] = base + local[i];
}

// Scatter points into bucket-sorted order: xs[pos] = (px,py,pz, bitcast(n)).
__global__ __launch_bounds__(256) void bucket_scatter(
    const float* __restrict__ x, unsigned* __restrict__ cursor,
    float4* __restrict__ xs) {
  int n = blockIdx.x * 256 + threadIdx.x;
  float px = x[n * 3 + 0];
  float py = x[n * 3 + 1];
  float pz = x[n * 3 + 2];
  unsigned b = morton_bucket(px, py, pz);
  unsigned pos = atomicAdd(&cursor[b], 1u);
  xs[pos] = make_float4(px, py, pz, __uint_as_float((unsigned)n));
}

// ---------------------------------------------------------------------------
// Sampling core: 8 lanes/point, each lane owns 8 channels (half8 = 16 B).
// Corner gather = 8 lanes x 16 B = 128 B contiguous (one cell line).
// fp16 source + fp32 accumulate -> compiler emits v_fma_mix_f32
// (8 VALU/corner vs 16 for the old bf16 shift/mask unpack).
// ---------------------------------------------------------------------------
__device__ __forceinline__ void fma_mix8(half8 v, float w, float* acc) {
#pragma unroll
  for (int j = 0; j < 8; ++j) acc[j] = fmaf((float)v[j], w, acc[j]);
}

__device__ __forceinline__ void sample_plane(const ushort_t* __restrict__ tp,
                                             float u, float v, int c8,
                                             float* acc) {
  float ix = fmaf(u, 0.5f * (float)(RES - 1), 0.5f * (float)(RES - 1));
  float iy = fmaf(v, 0.5f * (float)(RES - 1), 0.5f * (float)(RES - 1));
  float fx0 = floorf(ix), fy0 = floorf(iy);
  // weights from UNCLAMPED floor coords (reference semantics)
  float wx1 = ix - fx0, wy1 = iy - fy0;
  float wx0 = fx0 + 1.0f - ix, wy0 = fy0 + 1.0f - iy;
  int x0 = min(max((int)fx0, 0), RES - 1);
  int y0 = min(max((int)fy0, 0), RES - 1);
  int x1 = min(max((int)fx0 + 1, 0), RES - 1);
  int y1 = min(max((int)fy0 + 1, 0), RES - 1);

  const half8 v00 = *(const half8*)(tp + (size_t)(y0 * RES + x0) * FEAT + c8);
  const half8 v01 = *(const half8*)(tp + (size_t)(y0 * RES + x1) * FEAT + c8);
  const half8 v10 = *(const half8*)(tp + (size_t)(y1 * RES + x0) * FEAT + c8);
  const half8 v11 = *(const half8*)(tp + (size_t)(y1 * RES + x1) * FEAT + c8);

  fma_mix8(v00, wx0 * wy0, acc);
  fma_mix8(v01, wx1 * wy0, acc);
  fma_mix8(v10, wx0 * wy1, acc);
  fma_mix8(v11, wx1 * wy1, acc);
}

// ---------------------------------------------------------------------------
// Sorted sampling: block b (XCD-chunk swizzled) handles 32 consecutive
// bucket-sorted points. Each XCD works one Morton octant -> gathers hit
// the private 4 MB L2 / LLC with strong temporal locality.
// ---------------------------------------------------------------------------
__global__ __launch_bounds__(256) void triplane_sample_sorted(
    const float4* __restrict__ xs, const ushort_t* __restrict__ tps,
    float* __restrict__ out) {
  int bid = blockIdx.x;
  int swz = (bid & 7) * SAMPLE_CPX + (bid >> 3);  // XCD-chunked (bijective)
  int p = swz * 32 + (threadIdx.x >> 3);          // sorted point slot
  int c8 = (threadIdx.x & 7) << 3;                // channel group base

  v4f pt = __builtin_nontemporal_load((const v4f*)xs + p);  // 8 lanes share
  unsigned n = __float_as_uint(pt.w);             // original point index

  float acc[8] = {0.f, 0.f, 0.f, 0.f, 0.f, 0.f, 0.f, 0.f};
  sample_plane(tps, pt.x, pt.y, c8, acc);                    // xy: (x, y)
  sample_plane(tps + PLANE_ELEMS, pt.x, pt.z, c8, acc);      // xz: (x, z)
  sample_plane(tps + 2 * PLANE_ELEMS, pt.y, pt.z, c8, acc);  // yz: (y, z)

  const float s = 1.0f / 3.0f;
  v4f lo = {acc[0] * s, acc[1] * s, acc[2] * s, acc[3] * s};
  v4f hi = {acc[4] * s, acc[5] * s, acc[6] * s, acc[7] * s};
  float* o = out + (size_t)n * FEAT + c8;
  __builtin_nontemporal_store(lo, (v4f*)o);
  __builtin_nontemporal_store(hi, (v4f*)(o + 4));
}

// ---------------------------------------------------------------------------
// Unsorted fallback: ws fits fp16 atlas but not sort buffers.
// ---------------------------------------------------------------------------
__global__ __launch_bounds__(256) void transpose_only(
    const float* __restrict__ pxy, const float* __restrict__ pxz,
    const float* __restrict__ pyz, ushort_t* __restrict__ dst) {
  __shared__ ushort_t tile[64][72];
  const int plane = blockIdx.y;
  const float* src = (plane == 0) ? pxy : ((plane == 1) ? pxz : pyz);
  ushort_t* out = dst + (size_t)plane * PLANE_ELEMS;
  const int p0 = blockIdx.x * 64;
  const int tid = threadIdx.x;
#pragma unroll
  for (int k = 0; k < 4; ++k) {
    int c = (tid >> 4) + k * 16;
    int pp = (tid & 15) * 4;
    v4f v = *(const v4f*)(src + (size_t)c * (RES * RES) + p0 + pp);
    tile[pp + 0][c] = f2h(v.x);
    tile[pp + 1][c] = f2h(v.y);
    tile[pp + 2][c] = f2h(v.z);
    tile[pp + 3][c] = f2h(v.w);
  }
  __syncthreads();
#pragma unroll
  for (int k = 0; k < 2; ++k) {
    int idx = k * 256 + tid;
    int pp = idx >> 3;
    int c8 = (idx & 7) * 8;
    uint4 v = *(const uint4*)&tile[pp][c8];
    *(uint4*)(out + (size_t)(p0 + pp) * FEAT + c8) = v;
  }
}

__global__ __launch_bounds__(256) void triplane_sample_f16(
    const float* __restrict__ x, const ushort_t* __restrict__ tps,
    float* __restrict__ out) {
  int t = blockIdx.x * 256 + threadIdx.x;
  int n = t >> 3;
  int c8 = (t & 7) << 3;
  float px = __builtin_nontemporal_load(x + n * 3 + 0);
  float py = __builtin_nontemporal_load(x + n * 3 + 1);
  float pz = __builtin_nontemporal_load(x + n * 3 + 2);
  float acc[8] = {0.f, 0.f, 0.f, 0.f, 0.f, 0.f, 0.f, 0.f};
  sample_plane(tps, px, py, c8, acc);
  sample_plane(tps + PLANE_ELEMS, px, pz, c8, acc);
  sample_plane(tps + 2 * PLANE_ELEMS, py, pz, c8, acc);
  const float s = 1.0f / 3.0f;
  v4f lo = {acc[0] * s, acc[1] * s, acc[2] * s, acc[3] * s};
  v4f hi = {acc[4] * s, acc[5] * s, acc[6] * s, acc[7] * s};
  float* o = out + (size_t)n * FEAT + c8;
  __builtin_nontemporal_store(lo, (v4f*)o);
  __builtin_nontemporal_store(hi, (v4f*)(o + 4));
}

// ---------------------------------------------------------------------------
// Last-resort fallback: direct gather from native [C,H,W] layout.
// ---------------------------------------------------------------------------
__device__ __forceinline__ float sample_one(const float* __restrict__ pc,
                                            float u, float v) {
  float ix = (u + 1.0f) * 0.5f * (float)(RES - 1);
  float iy = (v + 1.0f) * 0.5f * (float)(RES - 1);
  float fx0 = floorf(ix), fy0 = floorf(iy);
  float wx1 = ix - fx0, wy1 = iy - fy0;
  float wx0 = fx0 + 1.0f - ix, wy0 = fy0 + 1.0f - iy;
  int x0 = min(max((int)fx0, 0), RES - 1);
  int y0 = min(max((int)fy0, 0), RES - 1);
  int x1 = min(max((int)fx0 + 1, 0), RES - 1);
  int y1 = min(max((int)fy0 + 1, 0), RES - 1);
  return pc[y0 * RES + x0] * (wx0 * wy0) + pc[y0 * RES + x1] * (wx1 * wy0) +
         pc[y1 * RES + x0] * (wx0 * wy1) + pc[y1 * RES + x1] * (wx1 * wy1);
}

__global__ __launch_bounds__(256) void triplane_direct(
    const float* __restrict__ x, const float* __restrict__ pxy,
    const float* __restrict__ pxz, const float* __restrict__ pyz,
    float* __restrict__ out) {
  int t = blockIdx.x * 256 + threadIdx.x;
  int n = t >> 6;
  int c = t & 63;
  float px = x[n * 3 + 0];
  float py = x[n * 3 + 1];
  float pz = x[n * 3 + 2];
  const size_t cs = (size_t)c * (RES * RES);
  float acc = sample_one(pxy + cs, px, py) + sample_one(pxz + cs, px, pz) +
              sample_one(pyz + cs, py, pz);
  out[(size_t)n * FEAT + c] = acc * (1.0f / 3.0f);
}

extern "C" void kernel_launch(void* const* d_in, const int* in_sizes, int n_in,
                              void* d_out, int out_size, void* d_ws,
                              size_t ws_size, hipStream_t stream) {
  const float* x   = (const float*)d_in[0];
  const float* pxy = (const float*)d_in[1];
  const float* pxz = (const float*)d_in[2];
  const float* pyz = (const float*)d_in[3];
  float* out = (float*)d_out;

  const size_t tps_bytes = (size_t)3 * PLANE_ELEMS * sizeof(ushort_t);  // 24 MB
  const size_t xs_bytes  = (size_t)N_POINTS * sizeof(float4);           // 16 MB
  const size_t cnt_bytes = (size_t)NBUCKET * sizeof(unsigned);          // 128 KB
  const size_t need_sorted = tps_bytes + xs_bytes + 2 * cnt_bytes;      // ~40.3 MB

  if (ws_size >= need_sorted) {
    ushort_t* tps    = (ushort_t*)d_ws;
    float4* xs       = (float4*)((char*)d_ws + tps_bytes);
    unsigned* cursor = (unsigned*)((char*)d_ws + tps_bytes + xs_bytes);
    unsigned* hist   = cursor + NBUCKET;

    (void)hipMemsetAsync(hist, 0, cnt_bytes, stream);  // capturable
    prep_transpose_count<<<PREP_BLOCKS, 256, 0, stream>>>(pxy, pxz, pyz, tps,
                                                          x, hist);
    scan_hist<<<1, 1024, 0, stream>>>(hist, cursor);
    bucket_scatter<<<N_POINTS / 256, 256, 0, stream>>>(x, cursor, xs);
    triplane_sample_sorted<<<SAMPLE_BLOCKS, 256, 0, stream>>>(xs, tps, out);
  } else if (ws_size >= tps_bytes) {
    ushort_t* tps = (ushort_t*)d_ws;
    dim3 tgrid(RES * RES / 64, 3);
    transpose_only<<<tgrid, 256, 0, stream>>>(pxy, pxz, pyz, tps);
    triplane_sample_f16<<<(N_POINTS * 8) / 256, 256, 0, stream>>>(x, tps, out);
  } else {
    triplane_direct<<<(N_POINTS * 64) / 256, 256, 0, stream>>>(x, pxy, pxz,
                                                               pyz, out);
  }
}

// Round 4
// 469.618 us; speedup vs baseline: 1.0716x; 1.0061x over previous
//
#include <hip/hip_runtime.h>

#define N_POINTS 1048576
#define FEAT 64
#define RES 256
#define PLANE_ELEMS (FEAT * RES * RES)  // elements per plane (4.19M)

// Morton bucketing: 32 buckets per axis -> 32768 buckets, ~32 points each.
#define BUCKET_G 32
#define NBUCKET (BUCKET_G * BUCKET_G * BUCKET_G)

// Sorted sample kernel geometry: 32 points/block (8 lanes/point, 256 thr).
#define SAMPLE_BLOCKS (N_POINTS / 32)          // 32768
#define SAMPLE_CPX (SAMPLE_BLOCKS / 8)         // 4096 blocks per XCD chunk

// Fused prep kernel: first TRANSPOSE_BLOCKS do transpose, rest do bucket count.
#define TRANSPOSE_BLOCKS (3 * (RES * RES / 64))      // 3072
#define COUNT_BLOCKS (N_POINTS / 256)                // 4096
#define PREP_BLOCKS (TRANSPOSE_BLOCKS + COUNT_BLOCKS)

typedef unsigned short ushort_t;
typedef float v4f __attribute__((ext_vector_type(4)));       // native 16B vec
typedef _Float16 half8 __attribute__((ext_vector_type(8)));  // 8 fp16 = 16 B

// float -> fp16 bits (RTNE)
__device__ __forceinline__ ushort_t f2h(float f) {
  _Float16 h = (_Float16)f;
  return __builtin_bit_cast(unsigned short, h);
}

// ---------------------------------------------------------------------------
// Morton bucket helpers
// ---------------------------------------------------------------------------
__device__ __forceinline__ unsigned part1by2(unsigned v) {
  v &= 0x3FFu;
  v = (v | (v << 16)) & 0x030000FFu;
  v = (v | (v << 8)) & 0x0300F00Fu;
  v = (v | (v << 4)) & 0x030C30C3u;
  v = (v | (v << 2)) & 0x09249249u;
  return v;
}

__device__ __forceinline__ unsigned morton_bucket(float px, float py, float pz) {
  int bx = (int)((px + 1.0f) * (0.5f * BUCKET_G));
  int by = (int)((py + 1.0f) * (0.5f * BUCKET_G));
  int bz = (int)((pz + 1.0f) * (0.5f * BUCKET_G));
  bx = min(max(bx, 0), BUCKET_G - 1);
  by = min(max(by, 0), BUCKET_G - 1);
  bz = min(max(bz, 0), BUCKET_G - 1);
  return part1by2((unsigned)bx) | (part1by2((unsigned)by) << 1) |
         (part1by2((unsigned)bz) << 2);  // < 32768
}

// ---------------------------------------------------------------------------
// Fused prep: blocks [0,3072) transpose fp32 [C,H*W] -> fp16 [H*W,C];
// blocks [3072,7168) histogram the Morton buckets.
// ---------------------------------------------------------------------------
__global__ __launch_bounds__(256) void prep_transpose_count(
    const float* __restrict__ pxy, const float* __restrict__ pxz,
    const float* __restrict__ pyz, ushort_t* __restrict__ dst,
    const float* __restrict__ x, unsigned* __restrict__ hist) {
  const int b = blockIdx.x;
  const int tid = threadIdx.x;
  if (b >= TRANSPOSE_BLOCKS) {
    int n = (b - TRANSPOSE_BLOCKS) * 256 + tid;
    float px = x[n * 3 + 0];
    float py = x[n * 3 + 1];
    float pz = x[n * 3 + 2];
    atomicAdd(&hist[morton_bucket(px, py, pz)], 1u);
    return;
  }
  __shared__ ushort_t tile[64][72];  // [p][c], row = 144 B (16B-aligned)
  const int plane = b >> 10;                  // 0..2
  const int p0 = (b & 1023) * 64;
  const float* src = (plane == 0) ? pxy : ((plane == 1) ? pxz : pyz);
  ushort_t* out = dst + (size_t)plane * PLANE_ELEMS;
#pragma unroll
  for (int k = 0; k < 4; ++k) {
    int c = (tid >> 4) + k * 16;  // 0..63
    int pp = (tid & 15) * 4;      // 0..60, float4-aligned
    v4f v = __builtin_nontemporal_load(
        (const v4f*)(src + (size_t)c * (RES * RES) + p0 + pp));
    tile[pp + 0][c] = f2h(v.x);
    tile[pp + 1][c] = f2h(v.y);
    tile[pp + 2][c] = f2h(v.z);
    tile[pp + 3][c] = f2h(v.w);
  }
  __syncthreads();
#pragma unroll
  for (int k = 0; k < 2; ++k) {
    int idx = k * 256 + tid;
    int pp = idx >> 3;            // 0..63
    int c8 = (idx & 7) * 8;       // 0..56
    uint4 v = *(const uint4*)&tile[pp][c8];  // 16B-aligned LDS read
    *(uint4*)(out + (size_t)(p0 + pp) * FEAT + c8) = v;
  }
}

// Exclusive prefix sum over NBUCKET=32768 counts.
__global__ __launch_bounds__(1024) void scan_hist(
    const unsigned* __restrict__ hist, unsigned* __restrict__ cursor) {
  __shared__ unsigned part[1024];
  const int tid = threadIdx.x;
  unsigned local[32];
  unsigned s = 0;
#pragma unroll
  for (int i = 0; i < 32; ++i) {
    local[i] = s;                 // exclusive within chunk
    s += hist[tid * 32 + i];
  }
  part[tid] = s;
  __syncthreads();
  for (int off = 1; off < 1024; off <<= 1) {
    unsigned add = (tid >= off) ? part[tid - off] : 0u;
    __syncthreads();
    part[tid] += add;
    __syncthreads();
  }
  unsigned base = (tid == 0) ? 0u : part[tid - 1];
#pragma unroll
  for (int i = 0; i < 32; ++i) cursor[tid * 32 + i] = base + local[i];
}

// Scatter points into bucket-sorted order: xs[pos] = (px,py,pz, bitcast(n)).
__global__ __launch_bounds__(256) void bucket_scatter(
    const float* __restrict__ x, unsigned* __restrict__ cursor,
    float4* __restrict__ xs) {
  int n = blockIdx.x * 256 + threadIdx.x;
  float px = x[n * 3 + 0];
  float py = x[n * 3 + 1];
  float pz = x[n * 3 + 2];
  unsigned b = morton_bucket(px, py, pz);
  unsigned pos = atomicAdd(&cursor[b], 1u);
  xs[pos] = make_float4(px, py, pz, __uint_as_float((unsigned)n));
}

// ---------------------------------------------------------------------------
// Sampling core. 8 lanes/point, each lane owns 8 channels (half8 = 16 B).
// Address/weight computation is split from loads so that ALL 12 corner
// gathers can be issued back-to-back (12 loads in flight per wave instead
// of ~4 -> 3x latency hiding). Consumption happens afterwards.
// ---------------------------------------------------------------------------
struct PlaneRef {
  const half8 *p00, *p01, *p10, *p11;
  float w00, w01, w10, w11;
};

__device__ __forceinline__ PlaneRef plane_ref(const ushort_t* __restrict__ tp,
                                              float u, float v, int c8) {
  float ix = fmaf(u, 0.5f * (float)(RES - 1), 0.5f * (float)(RES - 1));
  float iy = fmaf(v, 0.5f * (float)(RES - 1), 0.5f * (float)(RES - 1));
  float fx0 = floorf(ix), fy0 = floorf(iy);
  // weights from UNCLAMPED floor coords (reference semantics)
  float wx1 = ix - fx0, wy1 = iy - fy0;
  float wx0 = fx0 + 1.0f - ix, wy0 = fy0 + 1.0f - iy;
  int x0 = min(max((int)fx0, 0), RES - 1);
  int y0 = min(max((int)fy0, 0), RES - 1);
  int x1 = min(max((int)fx0 + 1, 0), RES - 1);
  int y1 = min(max((int)fy0 + 1, 0), RES - 1);
  PlaneRef r;
  r.p00 = (const half8*)(tp + (size_t)(y0 * RES + x0) * FEAT + c8);
  r.p01 = (const half8*)(tp + (size_t)(y0 * RES + x1) * FEAT + c8);
  r.p10 = (const half8*)(tp + (size_t)(y1 * RES + x0) * FEAT + c8);
  r.p11 = (const half8*)(tp + (size_t)(y1 * RES + x1) * FEAT + c8);
  r.w00 = wx0 * wy0;
  r.w01 = wx1 * wy0;
  r.w10 = wx0 * wy1;
  r.w11 = wx1 * wy1;
  return r;
}

__device__ __forceinline__ void fma_mix8(half8 v, float w, float* acc) {
#pragma unroll
  for (int j = 0; j < 8; ++j) acc[j] = fmaf((float)v[j], w, acc[j]);
}

// All-12-loads-in-flight triplane sample body.
__device__ __forceinline__ void sample3(const ushort_t* __restrict__ tps,
                                        float px, float py, float pz, int c8,
                                        float* acc) {
  PlaneRef A = plane_ref(tps, px, py, c8);                    // xy: (x, y)
  PlaneRef B = plane_ref(tps + PLANE_ELEMS, px, pz, c8);      // xz: (x, z)
  PlaneRef C = plane_ref(tps + 2 * PLANE_ELEMS, py, pz, c8);  // yz: (y, z)

  // Issue all 12 independent 16-B gathers before any use.
  const half8 a00 = *A.p00, a01 = *A.p01, a10 = *A.p10, a11 = *A.p11;
  const half8 b00 = *B.p00, b01 = *B.p01, b10 = *B.p10, b11 = *B.p11;
  const half8 c00 = *C.p00, c01 = *C.p01, c10 = *C.p10, c11 = *C.p11;

  // Consume in the same accumulation order as before (plane xy, xz, yz).
  fma_mix8(a00, A.w00, acc);
  fma_mix8(a01, A.w01, acc);
  fma_mix8(a10, A.w10, acc);
  fma_mix8(a11, A.w11, acc);
  fma_mix8(b00, B.w00, acc);
  fma_mix8(b01, B.w01, acc);
  fma_mix8(b10, B.w10, acc);
  fma_mix8(b11, B.w11, acc);
  fma_mix8(c00, C.w00, acc);
  fma_mix8(c01, C.w01, acc);
  fma_mix8(c10, C.w10, acc);
  fma_mix8(c11, C.w11, acc);
}

// ---------------------------------------------------------------------------
// Sorted sampling: block b (XCD-chunk swizzled) handles 32 consecutive
// bucket-sorted points. Each XCD works one Morton octant -> gathers hit
// the private 4 MB L2 / LLC with strong temporal locality.
// ---------------------------------------------------------------------------
__global__ __launch_bounds__(256) void triplane_sample_sorted(
    const float4* __restrict__ xs, const ushort_t* __restrict__ tps,
    float* __restrict__ out) {
  int bid = blockIdx.x;
  int swz = (bid & 7) * SAMPLE_CPX + (bid >> 3);  // XCD-chunked (bijective)
  int p = swz * 32 + (threadIdx.x >> 3);          // sorted point slot
  int c8 = (threadIdx.x & 7) << 3;                // channel group base

  v4f pt = __builtin_nontemporal_load((const v4f*)xs + p);  // 8 lanes share
  unsigned n = __float_as_uint(pt.w);             // original point index

  float acc[8] = {0.f, 0.f, 0.f, 0.f, 0.f, 0.f, 0.f, 0.f};
  sample3(tps, pt.x, pt.y, pt.z, c8, acc);

  const float s = 1.0f / 3.0f;
  v4f lo = {acc[0] * s, acc[1] * s, acc[2] * s, acc[3] * s};
  v4f hi = {acc[4] * s, acc[5] * s, acc[6] * s, acc[7] * s};
  float* o = out + (size_t)n * FEAT + c8;
  __builtin_nontemporal_store(lo, (v4f*)o);
  __builtin_nontemporal_store(hi, (v4f*)(o + 4));
}

// ---------------------------------------------------------------------------
// Unsorted fallback: ws fits fp16 atlas but not sort buffers.
// ---------------------------------------------------------------------------
__global__ __launch_bounds__(256) void transpose_only(
    const float* __restrict__ pxy, const float* __restrict__ pxz,
    const float* __restrict__ pyz, ushort_t* __restrict__ dst) {
  __shared__ ushort_t tile[64][72];
  const int plane = blockIdx.y;
  const float* src = (plane == 0) ? pxy : ((plane == 1) ? pxz : pyz);
  ushort_t* out = dst + (size_t)plane * PLANE_ELEMS;
  const int p0 = blockIdx.x * 64;
  const int tid = threadIdx.x;
#pragma unroll
  for (int k = 0; k < 4; ++k) {
    int c = (tid >> 4) + k * 16;
    int pp = (tid & 15) * 4;
    v4f v = *(const v4f*)(src + (size_t)c * (RES * RES) + p0 + pp);
    tile[pp + 0][c] = f2h(v.x);
    tile[pp + 1][c] = f2h(v.y);
    tile[pp + 2][c] = f2h(v.z);
    tile[pp + 3][c] = f2h(v.w);
  }
  __syncthreads();
#pragma unroll
  for (int k = 0; k < 2; ++k) {
    int idx = k * 256 + tid;
    int pp = idx >> 3;
    int c8 = (idx & 7) * 8;
    uint4 v = *(const uint4*)&tile[pp][c8];
    *(uint4*)(out + (size_t)(p0 + pp) * FEAT + c8) = v;
  }
}

__global__ __launch_bounds__(256) void triplane_sample_f16(
    const float* __restrict__ x, const ushort_t* __restrict__ tps,
    float* __restrict__ out) {
  int t = blockIdx.x * 256 + threadIdx.x;
  int n = t >> 3;
  int c8 = (t & 7) << 3;
  float px = __builtin_nontemporal_load(x + n * 3 + 0);
  float py = __builtin_nontemporal_load(x + n * 3 + 1);
  float pz = __builtin_nontemporal_load(x + n * 3 + 2);
  float acc[8] = {0.f, 0.f, 0.f, 0.f, 0.f, 0.f, 0.f, 0.f};
  sample3(tps, px, py, pz, c8, acc);
  const float s = 1.0f / 3.0f;
  v4f lo = {acc[0] * s, acc[1] * s, acc[2] * s, acc[3] * s};
  v4f hi = {acc[4] * s, acc[5] * s, acc[6] * s, acc[7] * s};
  float* o = out + (size_t)n * FEAT + c8;
  __builtin_nontemporal_store(lo, (v4f*)o);
  __builtin_nontemporal_store(hi, (v4f*)(o + 4));
}

// ---------------------------------------------------------------------------
// Last-resort fallback: direct gather from native [C,H,W] layout.
// ---------------------------------------------------------------------------
__device__ __forceinline__ float sample_one(const float* __restrict__ pc,
                                            float u, float v) {
  float ix = (u + 1.0f) * 0.5f * (float)(RES - 1);
  float iy = (v + 1.0f) * 0.5f * (float)(RES - 1);
  float fx0 = floorf(ix), fy0 = floorf(iy);
  float wx1 = ix - fx0, wy1 = iy - fy0;
  float wx0 = fx0 + 1.0f - ix, wy0 = fy0 + 1.0f - iy;
  int x0 = min(max((int)fx0, 0), RES - 1);
  int y0 = min(max((int)fy0, 0), RES - 1);
  int x1 = min(max((int)fx0 + 1, 0), RES - 1);
  int y1 = min(max((int)fy0 + 1, 0), RES - 1);
  return pc[y0 * RES + x0] * (wx0 * wy0) + pc[y0 * RES + x1] * (wx1 * wy0) +
         pc[y1 * RES + x0] * (wx0 * wy1) + pc[y1 * RES + x1] * (wx1 * wy1);
}

__global__ __launch_bounds__(256) void triplane_direct(
    const float* __restrict__ x, const float* __restrict__ pxy,
    const float* __restrict__ pxz, const float* __restrict__ pyz,
    float* __restrict__ out) {
  int t = blockIdx.x * 256 + threadIdx.x;
  int n = t >> 6;
  int c = t & 63;
  float px = x[n * 3 + 0];
  float py = x[n * 3 + 1];
  float pz = x[n * 3 + 2];
  const size_t cs = (size_t)c * (RES * RES);
  float acc = sample_one(pxy + cs, px, py) + sample_one(pxz + cs, px, pz) +
              sample_one(pyz + cs, py, pz);
  out[(size_t)n * FEAT + c] = acc * (1.0f / 3.0f);
}

extern "C" void kernel_launch(void* const* d_in, const int* in_sizes, int n_in,
                              void* d_out, int out_size, void* d_ws,
                              size_t ws_size, hipStream_t stream) {
  const float* x   = (const float*)d_in[0];
  const float* pxy = (const float*)d_in[1];
  const float* pxz = (const float*)d_in[2];
  const float* pyz = (const float*)d_in[3];
  float* out = (float*)d_out;

  const size_t tps_bytes = (size_t)3 * PLANE_ELEMS * sizeof(ushort_t);  // 24 MB
  const size_t xs_bytes  = (size_t)N_POINTS * sizeof(float4);           // 16 MB
  const size_t cnt_bytes = (size_t)NBUCKET * sizeof(unsigned);          // 128 KB
  const size_t need_sorted = tps_bytes + xs_bytes + 2 * cnt_bytes;      // ~40.3 MB

  if (ws_size >= need_sorted) {
    ushort_t* tps    = (ushort_t*)d_ws;
    float4* xs       = (float4*)((char*)d_ws + tps_bytes);
    unsigned* cursor = (unsigned*)((char*)d_ws + tps_bytes + xs_bytes);
    unsigned* hist   = cursor + NBUCKET;

    (void)hipMemsetAsync(hist, 0, cnt_bytes, stream);  // capturable
    prep_transpose_count<<<PREP_BLOCKS, 256, 0, stream>>>(pxy, pxz, pyz, tps,
                                                          x, hist);
    scan_hist<<<1, 1024, 0, stream>>>(hist, cursor);
    bucket_scatter<<<N_POINTS / 256, 256, 0, stream>>>(x, cursor, xs);
    triplane_sample_sorted<<<SAMPLE_BLOCKS, 256, 0, stream>>>(xs, tps, out);
  } else if (ws_size >= tps_bytes) {
    ushort_t* tps = (ushort_t*)d_ws;
    dim3 tgrid(RES * RES / 64, 3);
    transpose_only<<<tgrid, 256, 0, stream>>>(pxy, pxz, pyz, tps);
    triplane_sample_f16<<<(N_POINTS * 8) / 256, 256, 0, stream>>>(x, tps, out);
  } else {
    triplane_direct<<<(N_POINTS * 64) / 256, 256, 0, stream>>>(x, pxy, pxz,
                                                               pyz, out);
  }
}

// Round 5
// 462.465 us; speedup vs baseline: 1.0882x; 1.0155x over previous
//
#include <hip/hip_runtime.h>

#define N_POINTS 1048576
#define FEAT 64
#define RES 256
#define PLANE_ELEMS (FEAT * RES * RES)  // elements per plane (4.19M)

// Morton bucketing: 32 buckets per axis -> 32768 buckets, ~32 points each.
#define BUCKET_G 32
#define NBUCKET (BUCKET_G * BUCKET_G * BUCKET_G)

// Sorted sample kernel geometry: 32 points/block (8 lanes/point, 256 thr).
#define SAMPLE_BLOCKS (N_POINTS / 32)          // 32768
#define SAMPLE_CPX (SAMPLE_BLOCKS / 8)         // 4096 blocks per XCD chunk

// Fused prep kernel: first TRANSPOSE_BLOCKS do transpose, rest do bucket count.
#define TRANSPOSE_BLOCKS (3 * (RES * RES / 64))      // 3072
#define COUNT_BLOCKS (N_POINTS / 256)                // 4096
#define PREP_BLOCKS (TRANSPOSE_BLOCKS + COUNT_BLOCKS)

typedef unsigned short ushort_t;
typedef float v4f __attribute__((ext_vector_type(4)));       // native 16B vec
typedef _Float16 half8 __attribute__((ext_vector_type(8)));  // 8 fp16 = 16 B

// float -> fp16 bits (RTNE)
__device__ __forceinline__ ushort_t f2h(float f) {
  _Float16 h = (_Float16)f;
  return __builtin_bit_cast(unsigned short, h);
}

// ---------------------------------------------------------------------------
// Tiled atlas addressing: fp16 atlas stored as 8x8-texel tiles, each tile
// 64 texels x 64 ch x 2 B = 8 KB contiguous. Kills the 32-KB row stride
// (= vL1D size -> same-set aliasing) of the flat [y][x][c] layout.
//   elem(y, x, c) = tile(y>>3, x>>3)*4096 + ((y&7)*8 + (x&7))*64 + c
// ---------------------------------------------------------------------------
__device__ __forceinline__ int tiled_elem(int y, int x, int c8) {
  return (((y >> 3) << 5 | (x >> 3)) << 12) + (((y & 7) << 3 | (x & 7)) << 6) +
         c8;
}

// ---------------------------------------------------------------------------
// Morton bucket helpers
// ---------------------------------------------------------------------------
__device__ __forceinline__ unsigned part1by2(unsigned v) {
  v &= 0x3FFu;
  v = (v | (v << 16)) & 0x030000FFu;
  v = (v | (v << 8)) & 0x0300F00Fu;
  v = (v | (v << 4)) & 0x030C30C3u;
  v = (v | (v << 2)) & 0x09249249u;
  return v;
}

__device__ __forceinline__ unsigned morton_bucket(float px, float py, float pz) {
  int bx = (int)((px + 1.0f) * (0.5f * BUCKET_G));
  int by = (int)((py + 1.0f) * (0.5f * BUCKET_G));
  int bz = (int)((pz + 1.0f) * (0.5f * BUCKET_G));
  bx = min(max(bx, 0), BUCKET_G - 1);
  by = min(max(by, 0), BUCKET_G - 1);
  bz = min(max(bz, 0), BUCKET_G - 1);
  return part1by2((unsigned)bx) | (part1by2((unsigned)by) << 1) |
         (part1by2((unsigned)bz) << 2);  // < 32768
}

// ---------------------------------------------------------------------------
// Fused prep: blocks [0,3072) transpose fp32 [C,H*W] -> tiled fp16 atlas;
// blocks [3072,7168) histogram the Morton buckets.
// Each transpose block handles a 64-texel strip of ONE row y (x = xb..xb+63),
// so its output is 8 tile-rows of 1 KB each -> stores stay fully coalesced.
// ---------------------------------------------------------------------------
__global__ __launch_bounds__(256) void prep_transpose_count(
    const float* __restrict__ pxy, const float* __restrict__ pxz,
    const float* __restrict__ pyz, ushort_t* __restrict__ dst,
    const float* __restrict__ x, unsigned* __restrict__ hist) {
  const int b = blockIdx.x;
  const int tid = threadIdx.x;
  if (b >= TRANSPOSE_BLOCKS) {
    int n = (b - TRANSPOSE_BLOCKS) * 256 + tid;
    float px = x[n * 3 + 0];
    float py = x[n * 3 + 1];
    float pz = x[n * 3 + 2];
    atomicAdd(&hist[morton_bucket(px, py, pz)], 1u);
    return;
  }
  __shared__ ushort_t tile[64][72];  // [xoff][c], row = 144 B (16B-aligned)
  const int plane = b >> 10;                  // 0..2
  const int p0 = (b & 1023) * 64;             // strip start (row-major pos)
  const int y = p0 >> 8;                      // row
  const int xb = p0 & 255;                    // strip x base (multiple of 64)
  const float* src = (plane == 0) ? pxy : ((plane == 1) ? pxz : pyz);
  ushort_t* out = dst + (size_t)plane * PLANE_ELEMS;
#pragma unroll
  for (int k = 0; k < 4; ++k) {
    int c = (tid >> 4) + k * 16;  // 0..63
    int pp = (tid & 15) * 4;      // 0..60, float4-aligned
    v4f v = __builtin_nontemporal_load(
        (const v4f*)(src + (size_t)c * (RES * RES) + p0 + pp));
    tile[pp + 0][c] = f2h(v.x);
    tile[pp + 1][c] = f2h(v.y);
    tile[pp + 2][c] = f2h(v.z);
    tile[pp + 3][c] = f2h(v.w);
  }
  __syncthreads();
#pragma unroll
  for (int k = 0; k < 2; ++k) {
    int idx = k * 256 + tid;
    int pp = idx >> 3;            // 0..63 (x offset within strip)
    int c8 = (idx & 7) * 8;       // 0..56
    uint4 v = *(const uint4*)&tile[pp][c8];  // 16B-aligned LDS read
    *(uint4*)(out + tiled_elem(y, xb + pp, c8)) = v;
  }
}

// Exclusive prefix sum over NBUCKET=32768 counts. One block of 1024 threads;
// per-thread 32 counts via 8 x uint4 (batched, latency-overlapped) +
// Hillis-Steele block scan of the 1024 partials.
__global__ __launch_bounds__(1024) void scan_hist(
    const uint4* __restrict__ hist4, unsigned* __restrict__ cursor) {
  __shared__ unsigned part[1024];
  const int tid = threadIdx.x;
  uint4 h[8];
#pragma unroll
  for (int i = 0; i < 8; ++i) h[i] = hist4[tid * 8 + i];  // all in flight
  unsigned vals[32];
#pragma unroll
  for (int i = 0; i < 8; ++i) {
    vals[i * 4 + 0] = h[i].x;
    vals[i * 4 + 1] = h[i].y;
    vals[i * 4 + 2] = h[i].z;
    vals[i * 4 + 3] = h[i].w;
  }
  unsigned local[32];
  unsigned s = 0;
#pragma unroll
  for (int i = 0; i < 32; ++i) {
    local[i] = s;                 // exclusive within chunk
    s += vals[i];
  }
  part[tid] = s;
  __syncthreads();
  for (int off = 1; off < 1024; off <<= 1) {
    unsigned add = (tid >= off) ? part[tid - off] : 0u;
    __syncthreads();
    part[tid] += add;
    __syncthreads();
  }
  unsigned base = (tid == 0) ? 0u : part[tid - 1];
  uint4* cur4 = (uint4*)cursor;
#pragma unroll
  for (int i = 0; i < 8; ++i) {
    uint4 o;
    o.x = base + local[i * 4 + 0];
    o.y = base + local[i * 4 + 1];
    o.z = base + local[i * 4 + 2];
    o.w = base + local[i * 4 + 3];
    cur4[tid * 8 + i] = o;
  }
}

// Scatter points into bucket-sorted order: xs[pos] = (px,py,pz, bitcast(n)).
__global__ __launch_bounds__(256) void bucket_scatter(
    const float* __restrict__ x, unsigned* __restrict__ cursor,
    float4* __restrict__ xs) {
  int n = blockIdx.x * 256 + threadIdx.x;
  float px = x[n * 3 + 0];
  float py = x[n * 3 + 1];
  float pz = x[n * 3 + 2];
  unsigned b = morton_bucket(px, py, pz);
  unsigned pos = atomicAdd(&cursor[b], 1u);
  xs[pos] = make_float4(px, py, pz, __uint_as_float((unsigned)n));
}

// ---------------------------------------------------------------------------
// Sampling core. 8 lanes/point, each lane owns 8 channels (half8 = 16 B).
// Corner gather = 8 lanes x 16 B = 128 B contiguous (one tiled texel).
// All 12 corner loads issued before any use.
// ---------------------------------------------------------------------------
struct PlaneRef {
  const half8 *p00, *p01, *p10, *p11;
  float w00, w01, w10, w11;
};

__device__ __forceinline__ PlaneRef plane_ref(const ushort_t* __restrict__ tp,
                                              float u, float v, int c8) {
  float ix = fmaf(u, 0.5f * (float)(RES - 1), 0.5f * (float)(RES - 1));
  float iy = fmaf(v, 0.5f * (float)(RES - 1), 0.5f * (float)(RES - 1));
  float fx0 = floorf(ix), fy0 = floorf(iy);
  // weights from UNCLAMPED floor coords (reference semantics)
  float wx1 = ix - fx0, wy1 = iy - fy0;
  float wx0 = fx0 + 1.0f - ix, wy0 = fy0 + 1.0f - iy;
  int x0 = min(max((int)fx0, 0), RES - 1);
  int y0 = min(max((int)fy0, 0), RES - 1);
  int x1 = min(max((int)fx0 + 1, 0), RES - 1);
  int y1 = min(max((int)fy0 + 1, 0), RES - 1);
  PlaneRef r;
  r.p00 = (const half8*)(tp + tiled_elem(y0, x0, c8));
  r.p01 = (const half8*)(tp + tiled_elem(y0, x1, c8));
  r.p10 = (const half8*)(tp + tiled_elem(y1, x0, c8));
  r.p11 = (const half8*)(tp + tiled_elem(y1, x1, c8));
  r.w00 = wx0 * wy0;
  r.w01 = wx1 * wy0;
  r.w10 = wx0 * wy1;
  r.w11 = wx1 * wy1;
  return r;
}

__device__ __forceinline__ void fma_mix8(half8 v, float w, float* acc) {
#pragma unroll
  for (int j = 0; j < 8; ++j) acc[j] = fmaf((float)v[j], w, acc[j]);
}

__device__ __forceinline__ void sample3(const ushort_t* __restrict__ tps,
                                        float px, float py, float pz, int c8,
                                        float* acc) {
  PlaneRef A = plane_ref(tps, px, py, c8);                    // xy: (x, y)
  PlaneRef B = plane_ref(tps + PLANE_ELEMS, px, pz, c8);      // xz: (x, z)
  PlaneRef C = plane_ref(tps + 2 * PLANE_ELEMS, py, pz, c8);  // yz: (y, z)

  // Issue all 12 independent 16-B gathers before any use.
  const half8 a00 = *A.p00, a01 = *A.p01, a10 = *A.p10, a11 = *A.p11;
  const half8 b00 = *B.p00, b01 = *B.p01, b10 = *B.p10, b11 = *B.p11;
  const half8 c00 = *C.p00, c01 = *C.p01, c10 = *C.p10, c11 = *C.p11;

  // Consume in the same accumulation order as the reference (xy, xz, yz).
  fma_mix8(a00, A.w00, acc);
  fma_mix8(a01, A.w01, acc);
  fma_mix8(a10, A.w10, acc);
  fma_mix8(a11, A.w11, acc);
  fma_mix8(b00, B.w00, acc);
  fma_mix8(b01, B.w01, acc);
  fma_mix8(b10, B.w10, acc);
  fma_mix8(b11, B.w11, acc);
  fma_mix8(c00, C.w00, acc);
  fma_mix8(c01, C.w01, acc);
  fma_mix8(c10, C.w10, acc);
  fma_mix8(c11, C.w11, acc);
}

// ---------------------------------------------------------------------------
// Sorted sampling: block b (XCD-chunk swizzled) handles 32 consecutive
// bucket-sorted points. Bucket footprint = a few contiguous 8-KB tiles per
// plane -> L1-resident, L2-local.
// ---------------------------------------------------------------------------
__global__ __launch_bounds__(256) void triplane_sample_sorted(
    const float4* __restrict__ xs, const ushort_t* __restrict__ tps,
    float* __restrict__ out) {
  int bid = blockIdx.x;
  int swz = (bid & 7) * SAMPLE_CPX + (bid >> 3);  // XCD-chunked (bijective)
  int p = swz * 32 + (threadIdx.x >> 3);          // sorted point slot
  int c8 = (threadIdx.x & 7) << 3;                // channel group base

  v4f pt = __builtin_nontemporal_load((const v4f*)xs + p);  // 8 lanes share
  unsigned n = __float_as_uint(pt.w);             // original point index

  float acc[8] = {0.f, 0.f, 0.f, 0.f, 0.f, 0.f, 0.f, 0.f};
  sample3(tps, pt.x, pt.y, pt.z, c8, acc);

  const float s = 1.0f / 3.0f;
  v4f lo = {acc[0] * s, acc[1] * s, acc[2] * s, acc[3] * s};
  v4f hi = {acc[4] * s, acc[5] * s, acc[6] * s, acc[7] * s};
  float* o = out + (size_t)n * FEAT + c8;
  __builtin_nontemporal_store(lo, (v4f*)o);
  __builtin_nontemporal_store(hi, (v4f*)(o + 4));
}

// ---------------------------------------------------------------------------
// Unsorted fallback: ws fits fp16 atlas but not sort buffers.
// ---------------------------------------------------------------------------
__global__ __launch_bounds__(256) void transpose_only(
    const float* __restrict__ pxy, const float* __restrict__ pxz,
    const float* __restrict__ pyz, ushort_t* __restrict__ dst) {
  __shared__ ushort_t tile[64][72];
  const int plane = blockIdx.y;
  const float* src = (plane == 0) ? pxy : ((plane == 1) ? pxz : pyz);
  ushort_t* out = dst + (size_t)plane * PLANE_ELEMS;
  const int p0 = blockIdx.x * 64;
  const int y = p0 >> 8;
  const int xb = p0 & 255;
  const int tid = threadIdx.x;
#pragma unroll
  for (int k = 0; k < 4; ++k) {
    int c = (tid >> 4) + k * 16;
    int pp = (tid & 15) * 4;
    v4f v = *(const v4f*)(src + (size_t)c * (RES * RES) + p0 + pp);
    tile[pp + 0][c] = f2h(v.x);
    tile[pp + 1][c] = f2h(v.y);
    tile[pp + 2][c] = f2h(v.z);
    tile[pp + 3][c] = f2h(v.w);
  }
  __syncthreads();
#pragma unroll
  for (int k = 0; k < 2; ++k) {
    int idx = k * 256 + tid;
    int pp = idx >> 3;
    int c8 = (idx & 7) * 8;
    uint4 v = *(const uint4*)&tile[pp][c8];
    *(uint4*)(out + tiled_elem(y, xb + pp, c8)) = v;
  }
}

__global__ __launch_bounds__(256) void triplane_sample_f16(
    const float* __restrict__ x, const ushort_t* __restrict__ tps,
    float* __restrict__ out) {
  int t = blockIdx.x * 256 + threadIdx.x;
  int n = t >> 3;
  int c8 = (t & 7) << 3;
  float px = __builtin_nontemporal_load(x + n * 3 + 0);
  float py = __builtin_nontemporal_load(x + n * 3 + 1);
  float pz = __builtin_nontemporal_load(x + n * 3 + 2);
  float acc[8] = {0.f, 0.f, 0.f, 0.f, 0.f, 0.f, 0.f, 0.f};
  sample3(tps, px, py, pz, c8, acc);
  const float s = 1.0f / 3.0f;
  v4f lo = {acc[0] * s, acc[1] * s, acc[2] * s, acc[3] * s};
  v4f hi = {acc[4] * s, acc[5] * s, acc[6] * s, acc[7] * s};
  float* o = out + (size_t)n * FEAT + c8;
  __builtin_nontemporal_store(lo, (v4f*)o);
  __builtin_nontemporal_store(hi, (v4f*)(o + 4));
}

// ---------------------------------------------------------------------------
// Last-resort fallback: direct gather from native [C,H,W] layout.
// ---------------------------------------------------------------------------
__device__ __forceinline__ float sample_one(const float* __restrict__ pc,
                                            float u, float v) {
  float ix = (u + 1.0f) * 0.5f * (float)(RES - 1);
  float iy = (v + 1.0f) * 0.5f * (float)(RES - 1);
  float fx0 = floorf(ix), fy0 = floorf(iy);
  float wx1 = ix - fx0, wy1 = iy - fy0;
  float wx0 = fx0 + 1.0f - ix, wy0 = fy0 + 1.0f - iy;
  int x0 = min(max((int)fx0, 0), RES - 1);
  int y0 = min(max((int)fy0, 0), RES - 1);
  int x1 = min(max((int)fx0 + 1, 0), RES - 1);
  int y1 = min(max((int)fy0 + 1, 0), RES - 1);
  return pc[y0 * RES + x0] * (wx0 * wy0) + pc[y0 * RES + x1] * (wx1 * wy0) +
         pc[y1 * RES + x0] * (wx0 * wy1) + pc[y1 * RES + x1] * (wx1 * wy1);
}

__global__ __launch_bounds__(256) void triplane_direct(
    const float* __restrict__ x, const float* __restrict__ pxy,
    const float* __restrict__ pxz, const float* __restrict__ pyz,
    float* __restrict__ out) {
  int t = blockIdx.x * 256 + threadIdx.x;
  int n = t >> 6;
  int c = t & 63;
  float px = x[n * 3 + 0];
  float py = x[n * 3 + 1];
  float pz = x[n * 3 + 2];
  const size_t cs = (size_t)c * (RES * RES);
  float acc = sample_one(pxy + cs, px, py) + sample_one(pxz + cs, px, pz) +
              sample_one(pyz + cs, py, pz);
  out[(size_t)n * FEAT + c] = acc * (1.0f / 3.0f);
}

extern "C" void kernel_launch(void* const* d_in, const int* in_sizes, int n_in,
                              void* d_out, int out_size, void* d_ws,
                              size_t ws_size, hipStream_t stream) {
  const float* x   = (const float*)d_in[0];
  const float* pxy = (const float*)d_in[1];
  const float* pxz = (const float*)d_in[2];
  const float* pyz = (const float*)d_in[3];
  float* out = (float*)d_out;

  const size_t tps_bytes = (size_t)3 * PLANE_ELEMS * sizeof(ushort_t);  // 24 MB
  const size_t xs_bytes  = (size_t)N_POINTS * sizeof(float4);           // 16 MB
  const size_t cnt_bytes = (size_t)NBUCKET * sizeof(unsigned);          // 128 KB
  const size_t need_sorted = tps_bytes + xs_bytes + 2 * cnt_bytes;      // ~40.3 MB

  if (ws_size >= need_sorted) {
    ushort_t* tps    = (ushort_t*)d_ws;
    float4* xs       = (float4*)((char*)d_ws + tps_bytes);
    unsigned* cursor = (unsigned*)((char*)d_ws + tps_bytes + xs_bytes);
    unsigned* hist   = cursor + NBUCKET;

    (void)hipMemsetAsync(hist, 0, cnt_bytes, stream);  // capturable
    prep_transpose_count<<<PREP_BLOCKS, 256, 0, stream>>>(pxy, pxz, pyz, tps,
                                                          x, hist);
    scan_hist<<<1, 1024, 0, stream>>>((const uint4*)hist, cursor);
    bucket_scatter<<<N_POINTS / 256, 256, 0, stream>>>(x, cursor, xs);
    triplane_sample_sorted<<<SAMPLE_BLOCKS, 256, 0, stream>>>(xs, tps, out);
  } else if (ws_size >= tps_bytes) {
    ushort_t* tps = (ushort_t*)d_ws;
    dim3 tgrid(RES * RES / 64, 3);
    transpose_only<<<tgrid, 256, 0, stream>>>(pxy, pxz, pyz, tps);
    triplane_sample_f16<<<(N_POINTS * 8) / 256, 256, 0, stream>>>(x, tps, out);
  } else {
    triplane_direct<<<(N_POINTS * 64) / 256, 256, 0, stream>>>(x, pxy, pxz,
                                                               pyz, out);
  }
}